// Round 12
// baseline (258.728 us; speedup 1.0000x reference)
//
#include <hip/hip_runtime.h>
#include <math.h>

#define Cc 1000
#define Cpad 1024
#define Dd 256
#define Bb 16384
#define NSs 200000
#define MOM 0.1f
#define EPSV 1e-12f
#define EPSC 0.10f
#define NEG_BIG (-3.4e38f)
#define IDX_BIG 0x7fffffff

// d_out layout (floats), concat of reference return tuple
#define OUT_CENTER 0
#define OUT_SRC (Cc*Dd)                       // 256000
#define OUT_C2C (OUT_SRC + (size_t)NSs*Dd)    // 51,456,000
#define OUT_INTER (OUT_C2C + Cc*2)            // 51,458,000

// ---- fallback scratch inside out_src region (float offsets), rows [0, SAFE_ROW) ----
#define SCR_SCORES 0                           // _Float16[Bb*Cpad] = 8,388,608 floats
#define SCR_FB 8388608                         // ushort[Bb*Dd]   (2,097,152 floats)
#define SCR_CB (SCR_FB + 2097152)              // ushort[Cpad*Dd] (131,072 floats)
#define SAFE_ROW 41472
#define E0 (SAFE_ROW * 64)                     // first gemm-phase-safe float4: 2,654,208
#define E_OWN_END 2097152                      // float4s of rows [0,32768) (scores region)
#define N4ALL (NSs * 64)                       // 12,800,000 float4 total

// ---- ws layout (floats) ----
#define WS_CHAT 0
#define WS_INVF 256000
#define WS_MARK 272384                         // int[NSs]
// ws-large mode extras:
#define WS_SCORES 472384                       // fp16[Bb*Cpad] = 8,388,608 float-equiv
#define WS_FB  (WS_SCORES + 8388608)           // 8,860,992
#define WS_CB  (WS_FB + 2097152)               // 10,958,144
#define WS_NEED_FLOATS 11089216                // ~44.4 MB

typedef __bf16    bf16x8 __attribute__((ext_vector_type(8)));
typedef float     f32x4  __attribute__((ext_vector_type(4)));
typedef _Float16  f16x8  __attribute__((ext_vector_type(8)));

__device__ __forceinline__ ushort f2bf(float f) {
    uint u = __float_as_uint(f);
    u += 0x7FFFu + ((u >> 16) & 1u);   // round-to-nearest-even
    return (ushort)(u >> 16);
}

__device__ __forceinline__ void gload16(const void* g, void* l) {
    __builtin_amdgcn_global_load_lds(
        (const __attribute__((address_space(1))) void*)g,
        (__attribute__((address_space(3))) void*)l, 16, 0, 0);
}

__device__ __forceinline__ void upd_top2(float& s1, int& i1, float& s2, int& i2,
                                         float s, int i) {
    // jax.lax.top_k tie semantics: larger value first; equal values -> lower index first
    if (s > s1 || (s == s1 && i < i1)) {
        s2 = s1; i2 = i1; s1 = s; i1 = i;
    } else if (s > s2 || (s == s2 && i < i2)) {
        s2 = s; i2 = i;
    }
}

__device__ __forceinline__ void copy_elem(const float* __restrict__ src,
                                          const float* __restrict__ feat,
                                          const int* __restrict__ mark,
                                          float* __restrict__ dst, int e) {
    int row = e >> 6;            // 64 float4 per row
    int m = mark[row];
    f32x4 v = __builtin_nontemporal_load((const f32x4*)src + e);
    if (m >= 0) {
        f32x4 f = *((const f32x4*)feat + (size_t)m * 64 + (e & 63));
        v = (1.0f - MOM) * v + MOM * f;
    }
    __builtin_nontemporal_store(v, (f32x4*)dst + e);
}

// ---------------- K_init: base copies (inter, c2c, center) + mark=-1 ----------------
#define N_INTER4 (Cc*Cc*2/4)     // 500000
#define N_C2C4   (Cc*2/4)        // 500
#define N_CM4    (Cc*Dd/4)       // 64000
#define N_MARK4  (NSs/4)         // 50000
#define N_INIT4  (N_INTER4 + N_C2C4 + N_CM4 + N_MARK4)

__global__ void k_init(const float4* __restrict__ interdist,
                       const float4* __restrict__ c2c,
                       const float4* __restrict__ cmem,
                       float4* __restrict__ out_inter,
                       float4* __restrict__ out_c2c,
                       float4* __restrict__ out_center,
                       int4* __restrict__ mark) {
    int i = blockIdx.x * blockDim.x + threadIdx.x;
    if (i < N_INTER4) {
        out_inter[i] = interdist[i];
    } else if (i < N_INTER4 + N_C2C4) {
        out_c2c[i - N_INTER4] = c2c[i - N_INTER4];
    } else if (i < N_INTER4 + N_C2C4 + N_CM4) {
        out_center[i - N_INTER4 - N_C2C4] = cmem[i - N_INTER4 - N_C2C4];
    } else if (i < N_INIT4) {
        int4 m; m.x = -1; m.y = -1; m.z = -1; m.w = -1;
        mark[i - N_INTER4 - N_C2C4 - N_CM4] = m;
    }
}

// ---------------- K1a: per-row norms, d1@label -> c2c, seg-sum atomics, feat->bf16,
// ----------------       + scatter mark[index[row]] = row ----------------
__global__ void k_rows_a(const float* __restrict__ feat, const float* __restrict__ cmem,
                         const int* __restrict__ label, const int* __restrict__ index,
                         float* __restrict__ out_center, float* __restrict__ out_c2c,
                         float* __restrict__ ws_invf, ushort* __restrict__ fb,
                         int* __restrict__ mark) {
    int wid  = threadIdx.x >> 6;
    int lane = threadIdx.x & 63;
    int row  = blockIdx.x * 4 + wid;
    if (row >= Bb) return;

    const float4 f4 = *(const float4*)(feat + (size_t)row * Dd + lane * 4);
    int lab = label[row];
    const float4 c4 = *(const float4*)(cmem + (size_t)lab * Dd + lane * 4);

    ushort4 h;
    h.x = f2bf(f4.x); h.y = f2bf(f4.y); h.z = f2bf(f4.z); h.w = f2bf(f4.w);
    *(ushort4*)(fb + (size_t)row * Dd + lane * 4) = h;

    float fs = f4.x*f4.x + f4.y*f4.y + f4.z*f4.z + f4.w*f4.w;
    float dt = f4.x*c4.x + f4.y*c4.y + f4.z*c4.z + f4.w*c4.w;
    float cs = c4.x*c4.x + c4.y*c4.y + c4.z*c4.z + c4.w*c4.w;
    #pragma unroll
    for (int off = 32; off; off >>= 1) {
        fs += __shfl_xor(fs, off);
        dt += __shfl_xor(dt, off);
        cs += __shfl_xor(cs, off);
    }
    float invf = 1.0f / fmaxf(sqrtf(fs), EPSV);
    if (lane == 0) {
        ws_invf[row] = invf;
        mark[index[row]] = row;
        float invc = 1.0f / fmaxf(sqrtf(cs), EPSV);
        float d1 = 0.5f * (1.0f - dt * invf * invc);
        atomicAdd(out_c2c + lab * 2,     1.0f);
        atomicAdd(out_c2c + lab * 2 + 1, d1);
    }
    atomicAdd(out_center + (size_t)lab * Dd + lane * 4 + 0, f4.x);
    atomicAdd(out_center + (size_t)lab * Dd + lane * 4 + 1, f4.y);
    atomicAdd(out_center + (size_t)lab * Dd + lane * 4 + 2, f4.z);
    atomicAdd(out_center + (size_t)lab * Dd + lane * 4 + 3, f4.w);
}

// ---------------- K2: normalize center_new -> chat (f32) + chat_bf16 (padded to 1024) ----------------
__global__ void k_chat(const float* __restrict__ out_center, float* __restrict__ chat,
                       ushort* __restrict__ cb) {
    int c = blockIdx.x;      // 0..1023
    int lane = threadIdx.x;  // 64
    if (c >= Cc) {
        ushort4 z; z.x = 0; z.y = 0; z.z = 0; z.w = 0;
        *(ushort4*)(cb + (size_t)c * Dd + lane * 4) = z;
        return;
    }
    float4 v = *(const float4*)(out_center + (size_t)c * Dd + lane * 4);
    float ss = v.x*v.x + v.y*v.y + v.z*v.z + v.w*v.w;
    #pragma unroll
    for (int off = 32; off; off >>= 1) ss += __shfl_xor(ss, off);
    float inv = 1.0f / fmaxf(sqrtf(ss), EPSV);
    float4 r; r.x = v.x*inv; r.y = v.y*inv; r.z = v.z*inv; r.w = v.w*inv;
    *(float4*)(chat + (size_t)c * Dd + lane * 4) = r;
    ushort4 h;
    h.x = f2bf(r.x); h.y = f2bf(r.y); h.z = f2bf(r.z); h.w = f2bf(r.w);
    *(ushort4*)(cb + (size_t)c * Dd + lane * 4) = h;
}

// ---------------- K4: role-split: GEMM tiles (b%4==0) CONCURRENT WITH
// ----------------      NT copy/lerp of out_src float4s [e0copy, N4ALL) ----------------
#define COPY_BLKS 3072
#define TOTAL_BLKS 4096

__global__ __launch_bounds__(256, 3) void k_gemm_copy(const ushort* __restrict__ fb,
                                                      const ushort* __restrict__ cb,
                                                      _Float16* __restrict__ scores,
                                                      const float* __restrict__ smem,
                                                      const float* __restrict__ feat,
                                                      const int* __restrict__ mark,
                                                      float* __restrict__ out_src,
                                                      int e0copy) {
    __shared__ __align__(16) char Asb[128 * 128];   // 16 KB
    __shared__ __align__(16) char Bsb[128 * 128];   // 16 KB

    int b = blockIdx.x;
    if ((b & 3) != 0) {
        // ---------- copy role: 3072 blocks, float4s [e0copy, N4ALL) ----------
        int c = (b - (b >> 2)) - 1;            // contiguous 0..3071 over b%4!=0
        int tid0 = c * 256 + threadIdx.x;
        for (int e = e0copy + tid0; e < N4ALL; e += COPY_BLKS * 256)
            copy_elem(smem, feat, mark, out_src, e);
        return;
    }
    int g = b >> 2;                             // 0..1023 gemm tile id
    int bx = g & 7;                             // col tile (Cpad/128)
    int by = g >> 3;                            // row tile (Bb/128)

    int tid  = threadIdx.x;
    int wid  = tid >> 6;
    int lane = tid & 63;
    int rl = lane & 15;
    int kg = lane >> 4;
    int wr = wid >> 1;          // 0..1 row half
    int wc = wid & 1;           // 0..1 col half
    int row0 = by * 128;
    int c0   = bx * 128;

    // pre-swizzled source chunk: lane writes physical chunk (lane&7) of LDS row
    // rloc+(lane>>3); it must fetch logical chunk (lane&7)^(lane>>3)
    int realb = ((lane & 7) ^ (lane >> 3)) << 4;    // byte offset within 128B row

    f32x4 acc[4][4];
    f32x4 z = {0.f, 0.f, 0.f, 0.f};
    #pragma unroll
    for (int mi = 0; mi < 4; mi++)
        #pragma unroll
        for (int ni = 0; ni < 4; ni++)
            acc[mi][ni] = z;

    for (int t = 0; t < 4; t++) {           // K steps of 64
        #pragma unroll
        for (int i = 0; i < 4; i++) {
            int rloc = wid * 32 + i * 8;
            int grow = row0 + rloc + (lane >> 3);
            gload16((const char*)(fb + (size_t)grow * Dd) + t * 128 + realb,
                    Asb + rloc * 128);
        }
        #pragma unroll
        for (int i = 0; i < 4; i++) {
            int rloc = wid * 32 + i * 8;
            int gcol = c0 + rloc + (lane >> 3);
            gload16((const char*)(cb + (size_t)gcol * Dd) + t * 128 + realb,
                    Bsb + rloc * 128);
        }
        asm volatile("s_waitcnt vmcnt(0)" ::: "memory");
        __syncthreads();

        // ---- fragments: swizzled ds_read_b128
        bf16x8 a[4][2], bfr[4][2];
        #pragma unroll
        for (int mi = 0; mi < 4; mi++)
            #pragma unroll
            for (int ks = 0; ks < 2; ks++) {
                int r = wr * 64 + mi * 16 + rl;
                int off = r * 128 + ((ks * 64 + kg * 16) ^ ((r & 7) << 4));
                a[mi][ks] = *(const bf16x8*)(Asb + off);
            }
        #pragma unroll
        for (int ni = 0; ni < 4; ni++)
            #pragma unroll
            for (int ks = 0; ks < 2; ks++) {
                int r = wc * 64 + ni * 16 + rl;
                int off = r * 128 + ((ks * 64 + kg * 16) ^ ((r & 7) << 4));
                bfr[ni][ks] = *(const bf16x8*)(Bsb + off);
            }

        // ---- 32 MFMAs
        #pragma unroll
        for (int ks = 0; ks < 2; ks++)
            #pragma unroll
            for (int mi = 0; mi < 4; mi++)
                #pragma unroll
                for (int ni = 0; ni < 4; ni++)
                    acc[mi][ni] = __builtin_amdgcn_mfma_f32_16x16x32_bf16(
                        a[mi][ks], bfr[ni][ks], acc[mi][ni], 0, 0, 0);

        __syncthreads();   // before next stage overwrites LDS
    }

    // ---- epilogue: C/D layout col=lane&15, row=(lane>>4)*4+reg [m89]; fp16 stores
    #pragma unroll
    for (int mi = 0; mi < 4; mi++) {
        int row = row0 + wr * 64 + mi * 16 + kg * 4;
        #pragma unroll
        for (int ni = 0; ni < 4; ni++) {
            int col = c0 + wc * 64 + ni * 16 + rl;
            #pragma unroll
            for (int rr = 0; rr < 4; rr++)
                scores[(size_t)(row + rr) * Cpad + col] = (_Float16)acc[mi][ni][rr];
        }
    }
}

// ---------------- K5: per-row top-2 of fp16 scores + f32 rescore; optional trailing copy ----------------
// doCopy (fallback mode only): block b exclusively owns scores rows 4b..4b+3 =
// out_src rows 8b..8b+7, so after its register loads it may overwrite them race-free;
// the dead fb/cb region rows [32768, SAFE_ROW) are grid-strided. In ws-large mode
// scratch lives in d_ws and doCopy=0 (gemm-phase copy covered everything).
__global__ __launch_bounds__(256) void k_sel(const _Float16* __restrict__ scores,
                                             const float* __restrict__ feat,
                                             const float* __restrict__ chat,
                                             const float* __restrict__ ws_invf,
                                             float* __restrict__ out_inter,
                                             const float* __restrict__ smem,
                                             const int* __restrict__ mark,
                                             float* __restrict__ out_src,
                                             int doCopy) {
    __shared__ int cnt[4];
    __shared__ int clist[4][32];
    int wid  = threadIdx.x >> 6;
    int lane = threadIdx.x & 63;
    int row  = blockIdx.x * 4 + wid;
    if (lane == 0) cnt[wid] = 0;

    const f16x8* sp = (const f16x8*)(scores + (size_t)row * Cpad);
    float v[16];
    float s1 = NEG_BIG, s2 = NEG_BIG;
    int   i1 = IDX_BIG, i2 = IDX_BIG;
    #pragma unroll
    for (int k = 0; k < 2; k++) {
        f16x8 q = sp[k * 64 + lane];            // cols k*512 + lane*8 .. +7 (coalesced 16B)
        int cbase = k * 512 + lane * 8;
        #pragma unroll
        for (int e = 0; e < 8; e++) {
            float f = (float)q[e];
            v[k*8 + e] = f;
            int c = cbase + e;
            if (c < Cc) upd_top2(s1, i1, s2, i2, f, c);
        }
    }
    // butterfly merge (disjoint column sets per lane -> no duplicate insertions)
    #pragma unroll
    for (int off = 1; off < 64; off <<= 1) {
        float ps1 = __shfl_xor(s1, off), ps2 = __shfl_xor(s2, off);
        int   pi1 = __shfl_xor(i1, off), pi2 = __shfl_xor(i2, off);
        upd_top2(s1, i1, s2, i2, ps1, pi1);
        upd_top2(s1, i1, s2, i2, ps2, pi2);
    }
    // candidates: every col with approx score within EPSC of the 2nd max
    float thr = s2 - EPSC;
    #pragma unroll
    for (int j = 0; j < 16; j++) {
        int c = (j >> 3) * 512 + lane * 8 + (j & 7);
        if (v[j] >= thr && c < Cc) {
            int slot = atomicAdd(&cnt[wid], 1);
            if (slot < 32) clist[wid][slot] = c;
        }
    }
    __syncthreads();   // all waves' score loads complete before any overwrite below
    int n = cnt[wid]; if (n > 32) n = 32;

    const float4 f4 = *(const float4*)(feat + (size_t)row * Dd + lane * 4);
    float S1 = NEG_BIG, S2 = NEG_BIG;
    int   I1 = IDX_BIG, I2 = IDX_BIG;
    for (int k = 0; k < n; k++) {
        int c = clist[wid][k];
        const float4 c4 = *(const float4*)(chat + (size_t)c * Dd + lane * 4);
        float d = f4.x*c4.x + f4.y*c4.y + f4.z*c4.z + f4.w*c4.w;
        #pragma unroll
        for (int off = 32; off; off >>= 1) d += __shfl_xor(d, off);
        upd_top2(S1, I1, S2, I2, d, c);   // order-independent result
    }
    if (lane == 0) {
        float inter = 0.5f * ws_invf[row] * (S1 - S2);
        size_t off2 = ((size_t)I1 * Cc + I2) * 2;
        atomicAdd(out_inter + off2,     1.0f);
        atomicAdd(out_inter + off2 + 1, inter);
    }

    if (doCopy) {
        // own 8 out_src rows (this block's score rows): float4s [b*512, b*512+512)
        int base = blockIdx.x * 512;
        #pragma unroll
        for (int it = 0; it < 2; it++) {
            int e = base + it * 256 + threadIdx.x;
            copy_elem(smem, feat, mark, out_src, e);
        }
        // dead fb/cb region: float4s [E_OWN_END, E0), grid-stride
        for (int e = E_OWN_END + blockIdx.x * 256 + threadIdx.x; e < E0;
             e += (Bb / 4) * 256)
            copy_elem(smem, feat, mark, out_src, e);
    }
}

extern "C" void kernel_launch(void* const* d_in, const int* in_sizes, int n_in,
                              void* d_out, int out_size, void* d_ws, size_t ws_size,
                              hipStream_t stream) {
    const float* feat   = (const float*)d_in[0];
    const float* cmem   = (const float*)d_in[1];
    const float* smem   = (const float*)d_in[2];
    const float* c2c    = (const float*)d_in[3];
    const float* inter  = (const float*)d_in[4];
    const int*   label  = (const int*)d_in[5];
    const int*   index  = (const int*)d_in[6];

    float* out = (float*)d_out;
    float* out_center = out + OUT_CENTER;
    float* out_src    = out + OUT_SRC;
    float* out_c2c    = out + OUT_C2C;
    float* out_inter  = out + OUT_INTER;

    float* ws    = (float*)d_ws;
    float* chat  = ws + WS_CHAT;
    float* winvf = ws + WS_INVF;
    int*   mark  = (int*)(ws + WS_MARK);

    // scratch placement: d_ws if large enough (full copy overlap), else out_src rows [0, SAFE_ROW)
    bool wsbig = ws_size >= (size_t)WS_NEED_FLOATS * 4;
    _Float16* scores;
    ushort *fb, *cb;
    int e0copy, doCopy;
    if (wsbig) {
        scores = (_Float16*)(ws + WS_SCORES);
        fb     = (ushort*)(ws + WS_FB);
        cb     = (ushort*)(ws + WS_CB);
        e0copy = 0;
        doCopy = 0;
    } else {
        scores = (_Float16*)(out_src + SCR_SCORES);
        fb     = (ushort*)(out_src + SCR_FB);
        cb     = (ushort*)(out_src + SCR_CB);
        e0copy = E0;
        doCopy = 1;
    }

    // 1) base copies + mark init
    k_init<<<(N_INIT4 + 255) / 256, 256, 0, stream>>>(
        (const float4*)inter, (const float4*)c2c, (const float4*)cmem,
        (float4*)out_inter, (float4*)out_c2c, (float4*)out_center,
        (int4*)mark);
    // 2) per-row norms, c2c, center atomics, feat->bf16, mark scatter
    k_rows_a<<<Bb / 4, 256, 0, stream>>>(feat, cmem, label, index,
                                         out_center, out_c2c, winvf, fb, mark);
    // 3) normalize center_new -> chat + chat_bf16 (padded)
    k_chat<<<Cpad, 64, 0, stream>>>(out_center, chat, cb);
    // 4) GEMM tiles CONCURRENT WITH copy of out_src float4s [e0copy, N4ALL)
    k_gemm_copy<<<TOTAL_BLKS, 256, 0, stream>>>(fb, cb, scores,
                                                smem, feat, mark, out_src, e0copy);
    // 5) top-2 + f32 rescore -> interdist atomics; fallback mode also copies
    //    the remaining out_src rows over its own dead scratch
    k_sel<<<Bb / 4, 256, 0, stream>>>(scores, feat, chat, winvf, out_inter,
                                      smem, mark, out_src, doCopy);
}